// Round 17
// baseline (67.545 us; speedup 1.0000x reference)
//
#include <hip/hip_runtime.h>
#include <hip/hip_bf16.h>

#define NTOK 1024
#define EMB  1024
#define NH   16
#define HD   64
#define NS   128

typedef unsigned short u16;
typedef unsigned int uint;
typedef __attribute__((ext_vector_type(8))) unsigned short ushort8v;
typedef __attribute__((ext_vector_type(8))) _Float16 half8v;
typedef __attribute__((ext_vector_type(4))) float f32x4;

__device__ __forceinline__ u16 f2h_bits(float f) {
  union { _Float16 h; u16 u; } x; x.h = (_Float16)f; return x.u;
}

__device__ __forceinline__ void gload16(const u16* g, u16* l) {
  __builtin_amdgcn_global_load_lds(
      (const __attribute__((address_space(1))) uint*)g,
      (__attribute__((address_space(3))) uint*)l, 16, 0, 0);
}

__device__ __forceinline__ ushort8v cvt8(const float4 x0, const float4 x1) {
  ushort8v p;
  p[0] = f2h_bits(x0.x); p[1] = f2h_bits(x0.y);
  p[2] = f2h_bits(x0.z); p[3] = f2h_bits(x0.w);
  p[4] = f2h_bits(x1.x); p[5] = f2h_bits(x1.y);
  p[6] = f2h_bits(x1.z); p[7] = f2h_bits(x1.w);
  return p;
}

// ---------------------------------------------------------------------------
// gemm4: C = A*B^T + bias, 1024^3, f16 MFMA, conversion FUSED into staging.
// 64x64 tile, BK=32, 4 waves. Per K-step: issue next tile's global loads
// (A: gload16 if A_F16, else f32->regs; B: f32->regs), compute current tile
// from LDS, vmcnt(0), cvt+ds_write next buffer, lgkmcnt(0)+barrier.
// 2 buffers suffice: the single barrier bounds wave skew to one iteration,
// and iter kt writes buf[(kt+1)&1] while all waves read buf[kt&1].
// Same XOR involution as gemm3: LDS[row][dc] = G[row][dc ^ ((row>>1)&3)].
// OUT_F16 && z==2 stores C transposed (Vt[d][token]).
// ---------------------------------------------------------------------------
template<bool A_F16, bool OUT_F16>
__global__ __launch_bounds__(256) void gemm4(
    const void* __restrict__ A0, const void* __restrict__ A1, const void* __restrict__ A2,
    const float* __restrict__ B0, const float* __restrict__ B1, const float* __restrict__ B2,
    const float* __restrict__ b0, const float* __restrict__ b1, const float* __restrict__ b2,
    void* __restrict__ Cp) {
  __shared__ u16 As[2][64 * 32];
  __shared__ u16 Bs[2][64 * 32];

  const int t = threadIdx.x;
  const int lane = t & 63;
  const int w = t >> 6;
  const int wr = w >> 1, wc = w & 1;
  const int m0 = blockIdx.y * 64;
  const int n0 = blockIdx.x * 64;
  const int z = blockIdx.z;

  const void*  Asel = (z == 0) ? A0 : ((z == 1) ? A1 : A2);
  const float* Bsel = (z == 0) ? B0 : ((z == 1) ? B1 : B2);
  const float* bsel = (z == 0) ? b0 : ((z == 1) ? b1 : b2);

  // ---- reg-staging thread mapping (8 elems/thread per operand) ----
  const int srow = t >> 2;                       // 0..63
  const int scC  = t & 3;                        // source chunk (8 elems)
  const int dcW  = scC ^ ((srow >> 1) & 3);      // swizzled dest chunk

  // B source (always fp32)
  const float* gB = Bsel + (size_t)(n0 + srow) * 1024 + scC * 8;
  // A source: f16 via gload16 (wave-uniform dest) or fp32 via regs
  const float* gAf = (const float*)Asel + (size_t)(m0 + srow) * 1024 + scC * 8;
  const int r_abs = w * 16 + (lane >> 2);
  const int schunk = (lane & 3) ^ ((r_abs >> 1) & 3);
  const u16* gAh = (const u16*)Asel + (size_t)(m0 + r_abs) * 1024 + schunk * 8;

  // ---- fragment read offsets (identical to gemm3) ----
  const int fr = lane & 15;
  const int fq = lane >> 4;
  int offA[2], offB[2];
#pragma unroll
  for (int m = 0; m < 2; m++) {
    const int R = wr * 32 + m * 16 + fr;
    offA[m] = R * 32 + (fq ^ ((R >> 1) & 3)) * 8;
  }
#pragma unroll
  for (int n = 0; n < 2; n++) {
    const int R = wc * 32 + n * 16 + fr;
    offB[n] = R * 32 + (fq ^ ((R >> 1) & 3)) * 8;
  }

  f32x4 acc[2][2];
#pragma unroll
  for (int m = 0; m < 2; m++)
#pragma unroll
    for (int n = 0; n < 2; n++) acc[m][n] = (f32x4){0.f, 0.f, 0.f, 0.f};

  // ---- prologue: stage tile 0 ----
  if constexpr (A_F16) {
    gload16(gAh, &As[0][(w * 16) * 32]);
  } else {
    const float4 a0 = *(const float4*)gAf;
    const float4 a1 = *(const float4*)(gAf + 4);
    *(ushort8v*)&As[0][srow * 32 + dcW * 8] = cvt8(a0, a1);
  }
  {
    const float4 x0 = *(const float4*)gB;
    const float4 x1 = *(const float4*)(gB + 4);
    *(ushort8v*)&Bs[0][srow * 32 + dcW * 8] = cvt8(x0, x1);
  }
  if constexpr (A_F16) asm volatile("s_waitcnt vmcnt(0)" ::: "memory");

  for (int kt = 0; kt < 32; kt++) {
    const int db = kt & 1;
    asm volatile("s_waitcnt lgkmcnt(0)" ::: "memory");
    __builtin_amdgcn_s_barrier();          // buf[db] fully written, visible
    __builtin_amdgcn_sched_barrier(0);

    // issue next tile's loads (land during compute)
    float4 a0n, a1n, b0n, b1n;
    if (kt < 31) {
      const int k1 = (kt + 1) * 32;
      if constexpr (A_F16) {
        gload16(gAh + k1, &As[db ^ 1][(w * 16) * 32]);
      } else {
        a0n = *(const float4*)(gAf + k1);
        a1n = *(const float4*)(gAf + k1 + 4);
      }
      b0n = *(const float4*)(gB + k1);
      b1n = *(const float4*)(gB + k1 + 4);
    }

    // compute current tile
    half8v a0 = *(const half8v*)&As[db][offA[0]];
    half8v a1 = *(const half8v*)&As[db][offA[1]];
    half8v bv0 = *(const half8v*)&Bs[db][offB[0]];
    half8v bv1 = *(const half8v*)&Bs[db][offB[1]];
    acc[0][0] = __builtin_amdgcn_mfma_f32_16x16x32_f16(a0, bv0, acc[0][0], 0, 0, 0);
    acc[0][1] = __builtin_amdgcn_mfma_f32_16x16x32_f16(a0, bv1, acc[0][1], 0, 0, 0);
    acc[1][0] = __builtin_amdgcn_mfma_f32_16x16x32_f16(a1, bv0, acc[1][0], 0, 0, 0);
    acc[1][1] = __builtin_amdgcn_mfma_f32_16x16x32_f16(a1, bv1, acc[1][1], 0, 0, 0);

    // write next buffer (after loads landed)
    if (kt < 31) {
      asm volatile("s_waitcnt vmcnt(0)" ::: "memory");
      if constexpr (!A_F16)
        *(ushort8v*)&As[db ^ 1][srow * 32 + dcW * 8] = cvt8(a0n, a1n);
      *(ushort8v*)&Bs[db ^ 1][srow * 32 + dcW * 8] = cvt8(b0n, b1n);
    }
  }

  u16*   Cb = (u16*)Cp   + ((size_t)z << 20);
  float* Cf = (float*)Cp + ((size_t)z << 20);

  if (OUT_F16 && z == 2) {
    // transposed store: Vt[col][row]
#pragma unroll
    for (int n = 0; n < 2; n++) {
      const int col = n0 + wc * 32 + n * 16 + fr;
      const float bn = bsel[col];
#pragma unroll
      for (int m = 0; m < 2; m++) {
        const int rbase = m0 + wr * 32 + m * 16 + fq * 4;
        ushort4 pk;
        pk.x = f2h_bits(acc[m][n][0] + bn);
        pk.y = f2h_bits(acc[m][n][1] + bn);
        pk.z = f2h_bits(acc[m][n][2] + bn);
        pk.w = f2h_bits(acc[m][n][3] + bn);
        *(ushort4*)&Cb[(size_t)col * 1024 + rbase] = pk;
      }
    }
    return;
  }

#pragma unroll
  for (int n = 0; n < 2; n++) {
    const int col = n0 + wc * 32 + n * 16 + fr;
    const float bn = bsel[col];
#pragma unroll
    for (int m = 0; m < 2; m++) {
      const int rbase = m0 + wr * 32 + m * 16 + fq * 4;
#pragma unroll
      for (int r = 0; r < 4; r++) {
        const float val = acc[m][n][r] + bn;
        if constexpr (OUT_F16)
          Cb[(size_t)(rbase + r) * 1024 + col] = f2h_bits(val);
        else
          Cf[(size_t)(rbase + r) * 1024 + col] = val;
      }
    }
  }
}

// ---------------------------------------------------------------------------
// attn12: attn11 (triple-buffered K/V, one barrier/tile, STAGE after barrier
// — validated R16) with the bitmask build FUSED into the prologue
// (LDS atomicOr over samples; idempotent+commutative -> deterministic).
// ---------------------------------------------------------------------------
__global__ __launch_bounds__(256) void attn12(const u16* __restrict__ Qh,
                                              const u16* __restrict__ Kh,
                                              const u16* __restrict__ Vtg,
                                              const int* __restrict__ samples,
                                              u16* __restrict__ O) {
  const int h  = blockIdx.x;
  const int qt = blockIdx.y;
  const int t  = threadIdx.x;
  const int wid = t >> 6;
  const int lane = t & 63;
  const int fr = lane & 15, fq = lane >> 4;

  __shared__ u16 Kl[3][128 * 64];    // 48 KB  [key][d] swizzled
  __shared__ u16 Vl[3][64 * 128];    // 48 KB  [d][key] swizzled
  __shared__ u16 Ps[4][16][136];     // 17.4 KB per-wave P
  __shared__ uint Ms[64][32];        // 8 KB mask

  // ---- build mask in LDS (replaces the separate mask kernel) ----
  {
    uint* msf = (uint*)Ms;           // 2048 words
#pragma unroll
    for (int j = 0; j < 8; j++) msf[t + j * 256] = 0u;
    __syncthreads();
    const int4* sp = (const int4*)(samples + (size_t)(qt * 64) * NS);  // 2048 int4
#pragma unroll
    for (int j = 0; j < 8; j++) {
      const int i4 = t + j * 256;
      const int4 c4 = sp[i4];
      const int row = i4 >> 5;       // 32 int4 per token row
      atomicOr(&msf[row * 32 + (c4.x >> 5)], 1u << (c4.x & 31));
      atomicOr(&msf[row * 32 + (c4.y >> 5)], 1u << (c4.y & 31));
      atomicOr(&msf[row * 32 + (c4.z >> 5)], 1u << (c4.z & 31));
      atomicOr(&msf[row * 32 + (c4.w >> 5)], 1u << (c4.w & 31));
    }
  }
  // atomics drained by the kt=0 top lgkmcnt(0)+barrier below.

  // ---- Q fragments ----
  half8v qa0, qa1;
  {
    const u16* qp = Qh + (size_t)(qt * 64 + wid * 16 + fr) * EMB + h * HD + fq * 8;
    qa0 = *(const half8v*)qp;
    qa1 = *(const half8v*)(qp + 32);
  }

  // ---- staging lane constants (identical to validated attn7/attn11) ----
  const int kRow = wid * 32 + (lane >> 3);
  const int kChO = ((lane & 7) ^ ((lane >> 3) & 7)) * 8;
  const u16* kBase = Kh + h * HD + kChO;
  const int vSub = lane >> 4;
  const int vCh  = lane & 15;
  const u16* vBase = Vtg + (size_t)h * HD * NTOK;

  auto STAGE = [&](int kt_, int b_) {
#pragma unroll
    for (int ii = 0; ii < 4; ii++) {
      const int row = kRow + ii * 8;
      gload16(kBase + (size_t)(kt_ * 128 + row) * EMB,
              &Kl[b_][(wid * 32 + ii * 8) * 64]);
    }
#pragma unroll
    for (int ii = 0; ii < 4; ii++) {
      const int d = wid * 16 + ii * 4 + vSub;
      const int ch = (vCh ^ (d & 15)) * 8;
      gload16(vBase + (size_t)d * NTOK + kt_ * 128 + ch,
              &Vl[b_][(wid * 16 + ii * 4) * 128]);
    }
  };

  f32x4 oacc[4];
#pragma unroll
  for (int ds = 0; ds < 4; ds++) oacc[ds] = (f32x4){0.f, 0.f, 0.f, 0.f};
  float lsum[4] = {0.f, 0.f, 0.f, 0.f};

  STAGE(0, 0);
  STAGE(1, 1);

#pragma unroll
  for (int kt = 0; kt < 8; kt++) {
    const int cb = kt % 3;
    if (kt < 7) {
      asm volatile("s_waitcnt vmcnt(8) lgkmcnt(0)" ::: "memory");
    } else {
      asm volatile("s_waitcnt vmcnt(0) lgkmcnt(0)" ::: "memory");
    }
    __builtin_amdgcn_s_barrier();
    __builtin_amdgcn_sched_barrier(0);
    if (kt < 6) STAGE(kt + 2, (kt + 2) % 3);   // buf[(kt-1)%3]: quiescent

    const u16* Kc = &Kl[cb][0];
    const u16* Vc = &Vl[cb][0];

    uint4 mq[4];
#pragma unroll
    for (int r = 0; r < 4; r++)
      mq[r] = *(const uint4*)&Ms[wid * 16 + fq * 4 + r][kt * 4];

    // ---- QK^T + mask + exp -> Ps ----
#pragma unroll
    for (int jb = 0; jb < 8; jb++) {
      f32x4 s = (f32x4){0.f, 0.f, 0.f, 0.f};
      const int R = jb * 16 + fr;
      const half8v b0 = *(const half8v*)&Kc[R * 64 + (fq ^ (fr & 7)) * 8];
      const half8v b1 = *(const half8v*)&Kc[R * 64 + ((4 + fq) ^ (fr & 7)) * 8];
      s = __builtin_amdgcn_mfma_f32_16x16x32_f16(qa0, b0, s, 0, 0, 0);
      s = __builtin_amdgcn_mfma_f32_16x16x32_f16(qa1, b1, s, 0, 0, 0);
#pragma unroll
      for (int r = 0; r < 4; r++) {
        const uint mw = (jb >> 1) == 0 ? mq[r].x
                      : (jb >> 1) == 1 ? mq[r].y
                      : (jb >> 1) == 2 ? mq[r].z : mq[r].w;
        const float p = ((mw >> ((jb & 1) * 16 + fr)) & 1u)
                            ? __expf(s[r] * 0.03125f) : 0.f;
        lsum[r] += p;
        Ps[wid][fq * 4 + r][jb * 16 + fr] = f2h_bits(p);
      }
    }
    asm volatile("s_waitcnt lgkmcnt(0)" ::: "memory");
    __builtin_amdgcn_sched_barrier(0);

    // ---- PV (pure MFMA cluster) ----
    __builtin_amdgcn_s_setprio(1);
#pragma unroll
    for (int jc = 0; jc < 4; jc++) {
      const half8v pa = *(const half8v*)&Ps[wid][fr][jc * 32 + fq * 8];
#pragma unroll
      for (int ds = 0; ds < 4; ds++) {
        const int d = ds * 16 + fr;
        const half8v vb = *(const half8v*)&Vc[d * 128 + ((jc * 4 + fq) ^ fr) * 8];
        oacc[ds] = __builtin_amdgcn_mfma_f32_16x16x32_f16(pa, vb, oacc[ds], 0, 0, 0);
      }
    }
    __builtin_amdgcn_s_setprio(0);
  }

  // ---- row-sum reduce ----
#pragma unroll
  for (int r = 0; r < 4; r++) {
    float v = lsum[r];
#pragma unroll
    for (int off = 1; off < 16; off <<= 1) v += __shfl_xor(v, off, 16);
    lsum[r] = v;
  }

#pragma unroll
  for (int ds = 0; ds < 4; ds++) {
#pragma unroll
    for (int r = 0; r < 4; r++) {
      O[(size_t)(qt * 64 + wid * 16 + fq * 4 + r) * EMB + h * HD + ds * 16 + fr] =
          f2h_bits(oacc[ds][r] / lsum[r]);
    }
  }
}

extern "C" void kernel_launch(void* const* d_in, const int* in_sizes, int n_in,
                              void* d_out, int out_size, void* d_ws, size_t ws_size,
                              hipStream_t stream) {
  const float* query = (const float*)d_in[0];
  const float* key   = (const float*)d_in[1];
  const float* value = (const float*)d_in[2];
  const float* Wq    = (const float*)d_in[3];
  const float* bq    = (const float*)d_in[4];
  const float* Wk    = (const float*)d_in[5];
  const float* bk    = (const float*)d_in[6];
  const float* Wv    = (const float*)d_in[7];
  const float* bv    = (const float*)d_in[8];
  const float* Wo    = (const float*)d_in[9];
  const float* bo    = (const float*)d_in[10];
  const int* samples = (const int*)d_in[11];
  float* out = (float*)d_out;

  // ws (u16 units): Qh @0 | Kh @1M | Vt @2M | O @3M   (8 MB total)
  u16* base = (u16*)d_ws;
  u16* Qh = base;
  u16* Kh = base + ((size_t)1 << 20);
  u16* Vt = base + ((size_t)2 << 20);
  u16* O  = base + ((size_t)3 << 20);

  // QKV projections: A = query/key/value fp32 (reg-cvt), B = Wq/Wk/Wv fp32
  // (reg-cvt), C = Qh/Kh/Vt (z=2 transposed). 3 launches total this round.
  gemm4<false, true><<<dim3(16, 16, 3), 256, 0, stream>>>(
      query, key, value, Wq, Wk, Wv, bq, bk, bv, Qh);

  attn12<<<dim3(NH, 16), 256, 0, stream>>>(Qh, Kh, Vt, samples, O);

  // out-projection: A = O f16 (gload16), B = Wo fp32 (reg-cvt), out fp32
  gemm4<true, false><<<dim3(16, 16, 1), 256, 0, stream>>>(
      O, O, O, Wo, Wo, Wo, bo, bo, bo, out);
}

// Round 18
// 63.487 us; speedup vs baseline: 1.0639x; 1.0639x over previous
//
#include <hip/hip_runtime.h>
#include <hip/hip_bf16.h>

#define NTOK 1024
#define EMB  1024
#define NH   16
#define HD   64
#define NS   128

typedef unsigned short u16;
typedef unsigned int uint;
typedef __attribute__((ext_vector_type(8))) unsigned short ushort8v;
typedef __attribute__((ext_vector_type(8))) _Float16 half8v;
typedef __attribute__((ext_vector_type(4))) float f32x4;

__device__ __forceinline__ u16 f2h_bits(float f) {
  union { _Float16 h; u16 u; } x; x.h = (_Float16)f; return x.u;
}

__device__ __forceinline__ void gload16(const u16* g, u16* l) {
  __builtin_amdgcn_global_load_lds(
      (const __attribute__((address_space(1))) uint*)g,
      (__attribute__((address_space(3))) uint*)l, 16, 0, 0);
}

// ---------------------------------------------------------------------------
// cvt_mask: z 0-2 = query/key/value fp32->f16, z 3-6 = Wq/Wk/Wv/Wo fp32->f16,
// z 7 = sampled-set bitmask build (frozen from R11).
// ---------------------------------------------------------------------------
__global__ __launch_bounds__(256) void cvt_mask(const float* __restrict__ S0,
                                                const float* __restrict__ S1,
                                                const float* __restrict__ S2,
                                                const float* __restrict__ S3,
                                                const float* __restrict__ S4,
                                                const float* __restrict__ S5,
                                                const float* __restrict__ S6,
                                                const int* __restrict__ samples,
                                                u16* __restrict__ D,
                                                uint* __restrict__ maskg) {
  const int z = blockIdx.y;
  const int t = threadIdx.x;
  if (z == 7) {
    __shared__ uint m[32];
    const int i = blockIdx.x;
    if (t < 32) m[t] = 0u;
    __syncthreads();
    if (t < NS) {
      const int c = samples[(size_t)i * NS + t];
      atomicOr(&m[c >> 5], 1u << (c & 31));
    }
    __syncthreads();
    if (t < 32) maskg[(size_t)i * 32 + t] = m[t];
    return;
  }
  const float* S;
  switch (z) {
    case 0: S = S0; break;
    case 1: S = S1; break;
    case 2: S = S2; break;
    case 3: S = S3; break;
    case 4: S = S4; break;
    case 5: S = S5; break;
    default: S = S6; break;
  }
  const int idx = blockIdx.x * 256 + t;
  const float4 f = ((const float4*)S)[idx];
  ushort4 p;
  p.x = f2h_bits(f.x); p.y = f2h_bits(f.y);
  p.z = f2h_bits(f.z); p.w = f2h_bits(f.w);
  ((ushort4*)(D + ((size_t)z << 20)))[idx] = p;
}

// ---------------------------------------------------------------------------
// gemm3: counted-vmcnt double-buffered 64x64 f16 GEMM (frozen from R11).
// Used for the output projection.
// ---------------------------------------------------------------------------
template<bool OUT_F16>
__global__ __launch_bounds__(256) void gemm3(const u16* __restrict__ Ab,
                                             const u16* __restrict__ Bb,
                                             const float* __restrict__ b0,
                                             const float* __restrict__ b1,
                                             const float* __restrict__ b2,
                                             void* __restrict__ Cp) {
  __shared__ u16 buf[2][2][64 * 32];

  const int t = threadIdx.x;
  const int lane = t & 63;
  const int w = t >> 6;
  const int wr = w >> 1, wc = w & 1;
  const int m0 = blockIdx.y * 64;
  const int n0 = blockIdx.x * 64;
  const int z = blockIdx.z;

  const u16* Az = Ab + ((size_t)z << 20);
  const u16* Bz = Bb + ((size_t)z << 20);
  const float* bsel = (z == 0) ? b0 : ((z == 1) ? b1 : b2);

  const int r_abs = w * 16 + (lane >> 2);
  const int schunk = (lane & 3) ^ ((r_abs >> 1) & 3);
  const u16* gA = Az + (size_t)(m0 + r_abs) * 1024 + schunk * 8;
  const u16* gB = Bz + (size_t)(n0 + r_abs) * 1024 + schunk * 8;
  u16* ldsA[2] = { &buf[0][0][(w * 16) * 32], &buf[1][0][(w * 16) * 32] };
  u16* ldsB[2] = { &buf[0][1][(w * 16) * 32], &buf[1][1][(w * 16) * 32] };

  const int fr = lane & 15;
  const int fq = lane >> 4;
  int offA[2], offB[2];
#pragma unroll
  for (int m = 0; m < 2; m++) {
    const int R = wr * 32 + m * 16 + fr;
    offA[m] = R * 32 + (fq ^ ((R >> 1) & 3)) * 8;
  }
#pragma unroll
  for (int n = 0; n < 2; n++) {
    const int R = wc * 32 + n * 16 + fr;
    offB[n] = R * 32 + (fq ^ ((R >> 1) & 3)) * 8;
  }

  f32x4 acc[2][2];
#pragma unroll
  for (int m = 0; m < 2; m++)
#pragma unroll
    for (int n = 0; n < 2; n++) acc[m][n] = (f32x4){0.f, 0.f, 0.f, 0.f};

  gload16(gA, ldsA[0]);
  gload16(gB, ldsB[0]);

  for (int kt = 0; kt < 32; kt++) {
    const int db = kt & 1;
    if (kt < 31) {
      const int k1 = (kt + 1) * 32;
      gload16(gA + k1, ldsA[db ^ 1]);
      gload16(gB + k1, ldsB[db ^ 1]);
      asm volatile("s_waitcnt vmcnt(2)" ::: "memory");
    } else {
      asm volatile("s_waitcnt vmcnt(0)" ::: "memory");
    }
    __builtin_amdgcn_s_barrier();
    __builtin_amdgcn_sched_barrier(0);

    const u16* cA = &buf[db][0][0];
    const u16* cB = &buf[db][1][0];
    half8v a0 = *(const half8v*)&cA[offA[0]];
    half8v a1 = *(const half8v*)&cA[offA[1]];
    half8v bv0 = *(const half8v*)&cB[offB[0]];
    half8v bv1 = *(const half8v*)&cB[offB[1]];
    acc[0][0] = __builtin_amdgcn_mfma_f32_16x16x32_f16(a0, bv0, acc[0][0], 0, 0, 0);
    acc[0][1] = __builtin_amdgcn_mfma_f32_16x16x32_f16(a0, bv1, acc[0][1], 0, 0, 0);
    acc[1][0] = __builtin_amdgcn_mfma_f32_16x16x32_f16(a1, bv0, acc[1][0], 0, 0, 0);
    acc[1][1] = __builtin_amdgcn_mfma_f32_16x16x32_f16(a1, bv1, acc[1][1], 0, 0, 0);

    asm volatile("s_waitcnt lgkmcnt(0)" ::: "memory");
    __builtin_amdgcn_s_barrier();
    __builtin_amdgcn_sched_barrier(0);
  }

  u16*   Cb = (u16*)Cp   + ((size_t)z << 20);
  float* Cf = (float*)Cp + ((size_t)z << 20);

  if (OUT_F16 && z == 2) {
#pragma unroll
    for (int n = 0; n < 2; n++) {
      const int col = n0 + wc * 32 + n * 16 + fr;
      const float bn = bsel[col];
#pragma unroll
      for (int m = 0; m < 2; m++) {
        const int rbase = m0 + wr * 32 + m * 16 + fq * 4;
        ushort4 pk;
        pk.x = f2h_bits(acc[m][n][0] + bn);
        pk.y = f2h_bits(acc[m][n][1] + bn);
        pk.z = f2h_bits(acc[m][n][2] + bn);
        pk.w = f2h_bits(acc[m][n][3] + bn);
        *(ushort4*)&Cb[(size_t)col * 1024 + rbase] = pk;
      }
    }
    return;
  }

#pragma unroll
  for (int n = 0; n < 2; n++) {
    const int col = n0 + wc * 32 + n * 16 + fr;
    const float bn = bsel[col];
#pragma unroll
    for (int m = 0; m < 2; m++) {
      const int rbase = m0 + wr * 32 + m * 16 + fq * 4;
#pragma unroll
      for (int r = 0; r < 4; r++) {
        const float val = acc[m][n][r] + bn;
        if constexpr (OUT_F16)
          Cb[(size_t)(rbase + r) * 1024 + col] = f2h_bits(val);
        else
          Cf[(size_t)(rbase + r) * 1024 + col] = val;
      }
    }
  }
}

// ---------------------------------------------------------------------------
// gemm3w: QKV GEMM with 64x128 tile (BM=64, BN=128), BK=32, 4 waves.
// Wave = 32x64 sub-tile, acc[2][4]: 6 ds_read_b128 -> 8 MFMA per step
// (vs gemm3's 4:4) => 25% less LDS traffic per FLOP. grid (8,16,3) = 384
// blocks = 1.5/CU. Same counted-vmcnt pipeline (3 gloads/thread/step ->
// vmcnt(3)). z==2 stores C transposed (Vt[d][token]).
// ---------------------------------------------------------------------------
__global__ __launch_bounds__(256) void gemm3w(const u16* __restrict__ Ab,
                                              const u16* __restrict__ Bb,
                                              const float* __restrict__ b0,
                                              const float* __restrict__ b1,
                                              const float* __restrict__ b2,
                                              u16* __restrict__ Cp) {
  __shared__ u16 As[2][64 * 32];    // 8 KB
  __shared__ u16 Bs[2][128 * 32];   // 16 KB

  const int t = threadIdx.x;
  const int lane = t & 63;
  const int w = t >> 6;
  const int wr = w >> 1, wc = w & 1;
  const int n0 = blockIdx.x * 128;
  const int m0 = blockIdx.y * 64;
  const int z = blockIdx.z;

  const u16* Az = Ab + ((size_t)z << 20);
  const u16* Bz = Bb + ((size_t)z << 20);
  const float* bsel = (z == 0) ? b0 : ((z == 1) ? b1 : b2);

  // A staging: wave w stages rows w*16..+15 (1 gload/thread)
  const int rA = w * 16 + (lane >> 2);
  const int cA_ = (lane & 3) ^ ((rA >> 1) & 3);
  const u16* gA = Az + (size_t)(m0 + rA) * 1024 + cA_ * 8;
  // B staging: wave w stages rows w*32..+31 (2 gloads/thread)
  const int rB0 = w * 32 + (lane >> 2);
  const int rB1 = rB0 + 16;
  const int cB0 = (lane & 3) ^ ((rB0 >> 1) & 3);
  const int cB1 = (lane & 3) ^ ((rB1 >> 1) & 3);
  const u16* gB0 = Bz + (size_t)(n0 + rB0) * 1024 + cB0 * 8;
  const u16* gB1 = Bz + (size_t)(n0 + rB1) * 1024 + cB1 * 8;

  const int fr = lane & 15;
  const int fq = lane >> 4;
  int offA[2], offB[4];
#pragma unroll
  for (int m = 0; m < 2; m++) {
    const int R = wr * 32 + m * 16 + fr;
    offA[m] = R * 32 + (fq ^ ((R >> 1) & 3)) * 8;
  }
#pragma unroll
  for (int n = 0; n < 4; n++) {
    const int R = wc * 64 + n * 16 + fr;
    offB[n] = R * 32 + (fq ^ ((R >> 1) & 3)) * 8;
  }

  f32x4 acc[2][4];
#pragma unroll
  for (int m = 0; m < 2; m++)
#pragma unroll
    for (int n = 0; n < 4; n++) acc[m][n] = (f32x4){0.f, 0.f, 0.f, 0.f};

  // prologue
  gload16(gA,  &As[0][(w * 16) * 32]);
  gload16(gB0, &Bs[0][(w * 32) * 32]);
  gload16(gB1, &Bs[0][(w * 32 + 16) * 32]);

  for (int kt = 0; kt < 32; kt++) {
    const int db = kt & 1;
    if (kt < 31) {
      const int k1 = (kt + 1) * 32;
      gload16(gA + k1,  &As[db ^ 1][(w * 16) * 32]);
      gload16(gB0 + k1, &Bs[db ^ 1][(w * 32) * 32]);
      gload16(gB1 + k1, &Bs[db ^ 1][(w * 32 + 16) * 32]);
      asm volatile("s_waitcnt vmcnt(3)" ::: "memory");
    } else {
      asm volatile("s_waitcnt vmcnt(0)" ::: "memory");
    }
    __builtin_amdgcn_s_barrier();
    __builtin_amdgcn_sched_barrier(0);

    half8v a[2], b[4];
#pragma unroll
    for (int m = 0; m < 2; m++) a[m] = *(const half8v*)&As[db][offA[m]];
#pragma unroll
    for (int n = 0; n < 4; n++) b[n] = *(const half8v*)&Bs[db][offB[n]];
#pragma unroll
    for (int m = 0; m < 2; m++)
#pragma unroll
      for (int n = 0; n < 4; n++)
        acc[m][n] = __builtin_amdgcn_mfma_f32_16x16x32_f16(a[m], b[n], acc[m][n], 0, 0, 0);

    asm volatile("s_waitcnt lgkmcnt(0)" ::: "memory");
    __builtin_amdgcn_s_barrier();
    __builtin_amdgcn_sched_barrier(0);
  }

  u16* Cb = Cp + ((size_t)z << 20);

  if (z == 2) {
    // transposed store: Vt[col][row]
#pragma unroll
    for (int n = 0; n < 4; n++) {
      const int col = n0 + wc * 64 + n * 16 + fr;
      const float bn = bsel[col];
#pragma unroll
      for (int m = 0; m < 2; m++) {
        const int rbase = m0 + wr * 32 + m * 16 + fq * 4;
        ushort4 pk;
        pk.x = f2h_bits(acc[m][n][0] + bn);
        pk.y = f2h_bits(acc[m][n][1] + bn);
        pk.z = f2h_bits(acc[m][n][2] + bn);
        pk.w = f2h_bits(acc[m][n][3] + bn);
        *(ushort4*)&Cb[(size_t)col * 1024 + rbase] = pk;
      }
    }
    return;
  }

#pragma unroll
  for (int n = 0; n < 4; n++) {
    const int col = n0 + wc * 64 + n * 16 + fr;
    const float bn = bsel[col];
#pragma unroll
    for (int m = 0; m < 2; m++) {
      const int rbase = m0 + wr * 32 + m * 16 + fq * 4;
#pragma unroll
      for (int r = 0; r < 4; r++)
        Cb[(size_t)(rbase + r) * 1024 + col] = f2h_bits(acc[m][n][r] + bn);
    }
  }
}

// ---------------------------------------------------------------------------
// attn13: attn7 schedule (validated) + swapped QK^T operands:
//   S^T = mfma(K_frag, Q_frag) -> D[key][q]: col=fr=q, row=fq*4+r=4 CONSECUTIVE
//   keys. Ps write becomes ONE b64 per jb (vs 4 strided u16); mask fetch is
//   one uint4 per lane per TILE (row = q = wid*16+fr, uniform across r).
//   lsum is a per-lane scalar (q=fr), reduced via 2 shfl_xor + LDS broadcast.
// Ms padded to [64][36] (row stride 144 B) so per-lane-row uint4 loads are
// conflict-free (bank stride 4, 2-way on b128 = free).
// ---------------------------------------------------------------------------
__global__ __launch_bounds__(256) void attn13(const u16* __restrict__ Qh,
                                              const u16* __restrict__ Kh,
                                              const u16* __restrict__ Vtg,
                                              const uint* __restrict__ maskg,
                                              u16* __restrict__ O) {
  const int h  = blockIdx.x;
  const int qt = blockIdx.y;
  const int t  = threadIdx.x;
  const int wid = t >> 6;
  const int lane = t & 63;
  const int fr = lane & 15, fq = lane >> 4;

  __shared__ u16 Kl[2][128 * 64];    // 32 KB  [key][d] swizzled
  __shared__ u16 Vl[2][64 * 128];    // 32 KB  [d][key] swizzled
  __shared__ u16 Ps[4][16][136];     // 17.4 KB per-wave P [q][key]
  __shared__ uint Ms[64][36];        // 9.2 KB mask (padded rows)
  __shared__ float lsums[4][16];

  // ---- stage mask: 2048 uint4, row-major [64 tokens][8 x uint4] ----
  {
    const uint4* src = (const uint4*)(maskg + (size_t)qt * 64 * 32);
#pragma unroll
    for (int j = 0; j < 8; j++) {
      const int i4 = t + j * 256;
      *(uint4*)&Ms[i4 >> 3][(i4 & 7) * 4] = src[i4];
    }
  }

  // ---- Q fragments ----
  half8v qa0, qa1;
  {
    const u16* qp = Qh + (size_t)(qt * 64 + wid * 16 + fr) * EMB + h * HD + fq * 8;
    qa0 = *(const half8v*)qp;
    qa1 = *(const half8v*)(qp + 32);
  }

  // ---- staging lane constants (identical to validated attn7) ----
  const int kRow = wid * 32 + (lane >> 3);
  const int kChO = ((lane & 7) ^ ((lane >> 3) & 7)) * 8;
  const u16* kBase = Kh + h * HD + kChO;
  const int vSub = lane >> 4;
  const int vCh  = lane & 15;
  const u16* vBase = Vtg + (size_t)h * HD * NTOK;

  auto STAGE = [&](int kt_, int b_) {
#pragma unroll
    for (int ii = 0; ii < 4; ii++) {
      const int row = kRow + ii * 8;
      gload16(kBase + (size_t)(kt_ * 128 + row) * EMB,
              &Kl[b_][(wid * 32 + ii * 8) * 64]);
    }
#pragma unroll
    for (int ii = 0; ii < 4; ii++) {
      const int d = wid * 16 + ii * 4 + vSub;
      const int ch = (vCh ^ (d & 15)) * 8;
      gload16(vBase + (size_t)d * NTOK + kt_ * 128 + ch,
              &Vl[b_][(wid * 16 + ii * 4) * 128]);
    }
  };

  f32x4 oacc[4];
#pragma unroll
  for (int ds = 0; ds < 4; ds++) oacc[ds] = (f32x4){0.f, 0.f, 0.f, 0.f};
  float lsum = 0.f;

  STAGE(0, 0);

  for (int kt = 0; kt < 8; kt++) {
    if (kt < 7) {
      STAGE(kt + 1, (kt + 1) & 1);
      asm volatile("s_waitcnt vmcnt(8)" ::: "memory");
    } else {
      asm volatile("s_waitcnt vmcnt(0)" ::: "memory");
    }
    asm volatile("s_waitcnt lgkmcnt(0)" ::: "memory");
    __builtin_amdgcn_s_barrier();
    __builtin_amdgcn_sched_barrier(0);

    const u16* Kc = &Kl[kt & 1][0];
    const u16* Vc = &Vl[kt & 1][0];

    // one mask uint4 per lane per tile: row = q = wid*16+fr, words kt*4..+3
    const uint4 mq = *(const uint4*)&Ms[wid * 16 + fr][kt * 4];

    // ---- S^T = K·Q^T + mask + exp -> Ps (b64 packed writes) ----
#pragma unroll
    for (int jb = 0; jb < 8; jb++) {
      f32x4 s = (f32x4){0.f, 0.f, 0.f, 0.f};
      const int R = jb * 16 + fr;
      const half8v b0 = *(const half8v*)&Kc[R * 64 + (fq ^ (fr & 7)) * 8];
      const half8v b1 = *(const half8v*)&Kc[R * 64 + ((4 + fq) ^ (fr & 7)) * 8];
      s = __builtin_amdgcn_mfma_f32_16x16x32_f16(b0, qa0, s, 0, 0, 0);
      s = __builtin_amdgcn_mfma_f32_16x16x32_f16(b1, qa1, s, 0, 0, 0);
      const uint mw = (jb >> 1) == 0 ? mq.x
                    : (jb >> 1) == 1 ? mq.y
                    : (jb >> 1) == 2 ? mq.z : mq.w;
      const int bb = (jb & 1) * 16 + fq * 4;
      ushort4 pk;
#pragma unroll
      for (int r = 0; r < 4; r++) {
        const float p = ((mw >> (bb + r)) & 1u) ? __expf(s[r] * 0.03125f) : 0.f;
        lsum += p;
        ((u16*)&pk)[r] = f2h_bits(p);
      }
      *(ushort4*)&Ps[wid][fr][jb * 16 + fq * 4] = pk;
    }
    asm volatile("s_waitcnt lgkmcnt(0)" ::: "memory");
    __builtin_amdgcn_sched_barrier(0);

    // ---- PV (pure MFMA cluster) ----
    __builtin_amdgcn_s_setprio(1);
#pragma unroll
    for (int jc = 0; jc < 4; jc++) {
      const half8v pa = *(const half8v*)&Ps[wid][fr][jc * 32 + fq * 8];
#pragma unroll
      for (int ds = 0; ds < 4; ds++) {
        const int d = ds * 16 + fr;
        const half8v vb = *(const half8v*)&Vc[d * 128 + ((jc * 4 + fq) ^ fr) * 8];
        oacc[ds] = __builtin_amdgcn_mfma_f32_16x16x32_f16(pa, vb, oacc[ds], 0, 0, 0);
      }
    }
    __builtin_amdgcn_s_setprio(0);
    __builtin_amdgcn_s_barrier();   // all waves done reading buf[kt&1]
  }

  // ---- row-sum finalize: lane has partial sum for q=fr over its fq-slice ----
  lsum += __shfl_xor(lsum, 16, 64);
  lsum += __shfl_xor(lsum, 32, 64);
  if (fq == 0) lsums[wid][fr] = lsum;
  asm volatile("s_waitcnt lgkmcnt(0)" ::: "memory");
  __builtin_amdgcn_sched_barrier(0);

  float ls[4];
#pragma unroll
  for (int r = 0; r < 4; r++) ls[r] = lsums[wid][fq * 4 + r];

#pragma unroll
  for (int ds = 0; ds < 4; ds++) {
#pragma unroll
    for (int r = 0; r < 4; r++) {
      O[(size_t)(qt * 64 + wid * 16 + fq * 4 + r) * EMB + h * HD + ds * 16 + fr] =
          f2h_bits(oacc[ds][r] / ls[r]);
    }
  }
}

extern "C" void kernel_launch(void* const* d_in, const int* in_sizes, int n_in,
                              void* d_out, int out_size, void* d_ws, size_t ws_size,
                              hipStream_t stream) {
  const float* query = (const float*)d_in[0];
  const float* key   = (const float*)d_in[1];
  const float* value = (const float*)d_in[2];
  const float* Wq    = (const float*)d_in[3];
  const float* bq    = (const float*)d_in[4];
  const float* Wk    = (const float*)d_in[5];
  const float* bk    = (const float*)d_in[6];
  const float* Wv    = (const float*)d_in[7];
  const float* bv    = (const float*)d_in[8];
  const float* Wo    = (const float*)d_in[9];
  const float* bo    = (const float*)d_in[10];
  const int* samples = (const int*)d_in[11];
  float* out = (float*)d_out;

  u16* base = (u16*)d_ws;
  u16* Xh = base;
  u16* Wh = base + ((size_t)3 << 20);
  u16* Qh = base + ((size_t)7 << 20);
  u16* Kh = base + ((size_t)8 << 20);
  u16* Vt = base + ((size_t)9 << 20);
  u16* O  = base + ((size_t)10 << 20);
  uint* maskg = (uint*)(base + ((size_t)11 << 20));

  cvt_mask<<<dim3(1024, 8), 256, 0, stream>>>(
      query, key, value, Wq, Wk, Wv, Wo, samples, Xh, maskg);

  gemm3w<<<dim3(8, 16, 3), 256, 0, stream>>>(Xh, Wh, bq, bk, bv, Qh);

  attn13<<<dim3(NH, 16), 256, 0, stream>>>(Qh, Kh, Vt, maskg, O);

  gemm3<false><<<dim3(16, 16, 1), 256, 0, stream>>>(O, Wh + ((size_t)3 << 20), bo, bo, bo, out);
}

// Round 19
// 57.195 us; speedup vs baseline: 1.1810x; 1.1100x over previous
//
#include <hip/hip_runtime.h>
#include <hip/hip_bf16.h>

#define NTOK 1024
#define EMB  1024
#define NH   16
#define HD   64
#define NS   128

typedef unsigned short u16;
typedef unsigned int uint;
typedef __attribute__((ext_vector_type(8))) unsigned short ushort8v;
typedef __attribute__((ext_vector_type(8))) _Float16 half8v;
typedef __attribute__((ext_vector_type(4))) float f32x4;

__device__ __forceinline__ u16 f2h_bits(float f) {
  union { _Float16 h; u16 u; } x; x.h = (_Float16)f; return x.u;
}

__device__ __forceinline__ void gload16(const u16* g, u16* l) {
  __builtin_amdgcn_global_load_lds(
      (const __attribute__((address_space(1))) uint*)g,
      (__attribute__((address_space(3))) uint*)l, 16, 0, 0);
}

// ---------------------------------------------------------------------------
// cvt_mask: z 0-2 = query/key/value fp32->f16, z 3-6 = Wq/Wk/Wv/Wo fp32->f16,
// z 7 = sampled-set bitmask build (frozen from R11).
// ---------------------------------------------------------------------------
__global__ __launch_bounds__(256) void cvt_mask(const float* __restrict__ S0,
                                                const float* __restrict__ S1,
                                                const float* __restrict__ S2,
                                                const float* __restrict__ S3,
                                                const float* __restrict__ S4,
                                                const float* __restrict__ S5,
                                                const float* __restrict__ S6,
                                                const int* __restrict__ samples,
                                                u16* __restrict__ D,
                                                uint* __restrict__ maskg) {
  const int z = blockIdx.y;
  const int t = threadIdx.x;
  if (z == 7) {
    __shared__ uint m[32];
    const int i = blockIdx.x;
    if (t < 32) m[t] = 0u;
    __syncthreads();
    if (t < NS) {
      const int c = samples[(size_t)i * NS + t];
      atomicOr(&m[c >> 5], 1u << (c & 31));
    }
    __syncthreads();
    if (t < 32) maskg[(size_t)i * 32 + t] = m[t];
    return;
  }
  const float* S;
  switch (z) {
    case 0: S = S0; break;
    case 1: S = S1; break;
    case 2: S = S2; break;
    case 3: S = S3; break;
    case 4: S = S4; break;
    case 5: S = S5; break;
    default: S = S6; break;
  }
  const int idx = blockIdx.x * 256 + t;
  const float4 f = ((const float4*)S)[idx];
  ushort4 p;
  p.x = f2h_bits(f.x); p.y = f2h_bits(f.y);
  p.z = f2h_bits(f.z); p.w = f2h_bits(f.w);
  ((ushort4*)(D + ((size_t)z << 20)))[idx] = p;
}

// ---------------------------------------------------------------------------
// gemm3: counted-vmcnt double-buffered 64x64 f16 GEMM (frozen from R11).
// ---------------------------------------------------------------------------
template<bool OUT_F16>
__global__ __launch_bounds__(256) void gemm3(const u16* __restrict__ Ab,
                                             const u16* __restrict__ Bb,
                                             const float* __restrict__ b0,
                                             const float* __restrict__ b1,
                                             const float* __restrict__ b2,
                                             void* __restrict__ Cp) {
  __shared__ u16 buf[2][2][64 * 32];

  const int t = threadIdx.x;
  const int lane = t & 63;
  const int w = t >> 6;
  const int wr = w >> 1, wc = w & 1;
  const int m0 = blockIdx.y * 64;
  const int n0 = blockIdx.x * 64;
  const int z = blockIdx.z;

  const u16* Az = Ab + ((size_t)z << 20);
  const u16* Bz = Bb + ((size_t)z << 20);
  const float* bsel = (z == 0) ? b0 : ((z == 1) ? b1 : b2);

  const int r_abs = w * 16 + (lane >> 2);
  const int schunk = (lane & 3) ^ ((r_abs >> 1) & 3);
  const u16* gA = Az + (size_t)(m0 + r_abs) * 1024 + schunk * 8;
  const u16* gB = Bz + (size_t)(n0 + r_abs) * 1024 + schunk * 8;
  u16* ldsA[2] = { &buf[0][0][(w * 16) * 32], &buf[1][0][(w * 16) * 32] };
  u16* ldsB[2] = { &buf[0][1][(w * 16) * 32], &buf[1][1][(w * 16) * 32] };

  const int fr = lane & 15;
  const int fq = lane >> 4;
  int offA[2], offB[2];
#pragma unroll
  for (int m = 0; m < 2; m++) {
    const int R = wr * 32 + m * 16 + fr;
    offA[m] = R * 32 + (fq ^ ((R >> 1) & 3)) * 8;
  }
#pragma unroll
  for (int n = 0; n < 2; n++) {
    const int R = wc * 32 + n * 16 + fr;
    offB[n] = R * 32 + (fq ^ ((R >> 1) & 3)) * 8;
  }

  f32x4 acc[2][2];
#pragma unroll
  for (int m = 0; m < 2; m++)
#pragma unroll
    for (int n = 0; n < 2; n++) acc[m][n] = (f32x4){0.f, 0.f, 0.f, 0.f};

  gload16(gA, ldsA[0]);
  gload16(gB, ldsB[0]);

  for (int kt = 0; kt < 32; kt++) {
    const int db = kt & 1;
    if (kt < 31) {
      const int k1 = (kt + 1) * 32;
      gload16(gA + k1, ldsA[db ^ 1]);
      gload16(gB + k1, ldsB[db ^ 1]);
      asm volatile("s_waitcnt vmcnt(2)" ::: "memory");
    } else {
      asm volatile("s_waitcnt vmcnt(0)" ::: "memory");
    }
    __builtin_amdgcn_s_barrier();
    __builtin_amdgcn_sched_barrier(0);

    const u16* cA = &buf[db][0][0];
    const u16* cB = &buf[db][1][0];
    half8v a0 = *(const half8v*)&cA[offA[0]];
    half8v a1 = *(const half8v*)&cA[offA[1]];
    half8v bv0 = *(const half8v*)&cB[offB[0]];
    half8v bv1 = *(const half8v*)&cB[offB[1]];
    acc[0][0] = __builtin_amdgcn_mfma_f32_16x16x32_f16(a0, bv0, acc[0][0], 0, 0, 0);
    acc[0][1] = __builtin_amdgcn_mfma_f32_16x16x32_f16(a0, bv1, acc[0][1], 0, 0, 0);
    acc[1][0] = __builtin_amdgcn_mfma_f32_16x16x32_f16(a1, bv0, acc[1][0], 0, 0, 0);
    acc[1][1] = __builtin_amdgcn_mfma_f32_16x16x32_f16(a1, bv1, acc[1][1], 0, 0, 0);

    asm volatile("s_waitcnt lgkmcnt(0)" ::: "memory");
    __builtin_amdgcn_s_barrier();
    __builtin_amdgcn_sched_barrier(0);
  }

  u16*   Cb = (u16*)Cp   + ((size_t)z << 20);
  float* Cf = (float*)Cp + ((size_t)z << 20);

  if (OUT_F16 && z == 2) {
#pragma unroll
    for (int n = 0; n < 2; n++) {
      const int col = n0 + wc * 32 + n * 16 + fr;
      const float bn = bsel[col];
#pragma unroll
      for (int m = 0; m < 2; m++) {
        const int rbase = m0 + wr * 32 + m * 16 + fq * 4;
        ushort4 pk;
        pk.x = f2h_bits(acc[m][n][0] + bn);
        pk.y = f2h_bits(acc[m][n][1] + bn);
        pk.z = f2h_bits(acc[m][n][2] + bn);
        pk.w = f2h_bits(acc[m][n][3] + bn);
        *(ushort4*)&Cb[(size_t)col * 1024 + rbase] = pk;
      }
    }
    return;
  }

#pragma unroll
  for (int n = 0; n < 2; n++) {
    const int col = n0 + wc * 32 + n * 16 + fr;
    const float bn = bsel[col];
#pragma unroll
    for (int m = 0; m < 2; m++) {
      const int rbase = m0 + wr * 32 + m * 16 + fq * 4;
#pragma unroll
      for (int r = 0; r < 4; r++) {
        const float val = acc[m][n][r] + bn;
        if constexpr (OUT_F16)
          Cb[(size_t)(rbase + r) * 1024 + col] = f2h_bits(val);
        else
          Cf[(size_t)(rbase + r) * 1024 + col] = val;
      }
    }
  }
}

// ---------------------------------------------------------------------------
// attn14: 8-wave (512-thread) blocks -> 2 waves/SIMD (all prior variants ran
// 1 wave/SIMD; the ~18us attn cost is serialized LDS latency with no partner
// wave to hide it). Wave (qg = wid>>1, kh = wid&1): 16 q-rows x key-half
// [kh*64, kh*64+64) of each 128-key tile. attn7's validated double-buffer
// schedule (2 barriers/tile, counted vmcnt) and swizzle formulas; per-wave
// work halves. Partial O/lsum: kh=1 publishes to LDS, kh=0 finalizes.
// LDS = 107 KB, 1 block/CU, grid (NH,16)=256 blocks.
// ---------------------------------------------------------------------------
__global__ __launch_bounds__(512) void attn14(const u16* __restrict__ Qh,
                                              const u16* __restrict__ Kh,
                                              const u16* __restrict__ Vtg,
                                              const uint* __restrict__ maskg,
                                              u16* __restrict__ O) {
  const int h  = blockIdx.x;
  const int qt = blockIdx.y;
  const int t  = threadIdx.x;
  const int wid = t >> 6;          // 0..7
  const int qg  = wid >> 1;        // q-row group 0..3
  const int kh  = wid & 1;         // key half 0..1
  const int lane = t & 63;
  const int fr = lane & 15, fq = lane >> 4;

  __shared__ u16 Kl[2][128 * 64];    // 32 KB  [key][d] swizzled
  __shared__ u16 Vl[2][64 * 128];    // 32 KB  [d][key] swizzled
  __shared__ u16 Ps[8][16][72];      // 18.4 KB per-wave P [q][key-half]
  __shared__ uint Ms[64][36];        // 9.2 KB mask (row stride 144B, 16B-aligned)
  __shared__ float Obuf[4][16][64];  // 16 KB partial O (kh=1 -> kh=0)
  __shared__ float Lbuf[4][16];      // partial lsum

  // ---- stage mask: 512 uint4 (one per thread) ----
  {
    const uint4* src = (const uint4*)(maskg + (size_t)qt * 64 * 32);
    *(uint4*)&Ms[t >> 3][(t & 7) * 4] = src[t];
  }

  // ---- Q fragments (16 q-rows per wave pair) ----
  half8v qa0, qa1;
  {
    const u16* qp = Qh + (size_t)(qt * 64 + qg * 16 + fr) * EMB + h * HD + fq * 8;
    qa0 = *(const half8v*)qp;
    qa1 = *(const half8v*)(qp + 32);
  }

  // ---- staging lane constants: 2 K + 2 V gloads/thread/tile ----
  // K rows: wid*16 + ii*8 + (lane>>3); row&7 == (lane>>3)&7 -> involution holds
  const int kR3 = lane >> 3;
  const int kChO = ((lane & 7) ^ (kR3 & 7)) * 8;
  const u16* kBase = Kh + h * HD + kChO;
  // V d-rows: wid*8 + ii*4 + (lane>>4)
  const int vSub = lane >> 4;
  const int vCh  = lane & 15;
  const u16* vBase = Vtg + (size_t)h * HD * NTOK;

  auto STAGE = [&](int kt_, int b_) {
#pragma unroll
    for (int ii = 0; ii < 2; ii++) {
      const int row = wid * 16 + ii * 8 + kR3;
      gload16(kBase + (size_t)(kt_ * 128 + row) * EMB,
              &Kl[b_][(wid * 16 + ii * 8) * 64]);
    }
#pragma unroll
    for (int ii = 0; ii < 2; ii++) {
      const int d = wid * 8 + ii * 4 + vSub;
      const int ch = (vCh ^ (d & 15)) * 8;
      gload16(vBase + (size_t)d * NTOK + kt_ * 128 + ch,
              &Vl[b_][(wid * 8 + ii * 4) * 128]);
    }
  };

  f32x4 oacc[4];
#pragma unroll
  for (int ds = 0; ds < 4; ds++) oacc[ds] = (f32x4){0.f, 0.f, 0.f, 0.f};
  float lsum[4] = {0.f, 0.f, 0.f, 0.f};

  STAGE(0, 0);

  for (int kt = 0; kt < 8; kt++) {
    if (kt < 7) {
      STAGE(kt + 1, (kt + 1) & 1);
      asm volatile("s_waitcnt vmcnt(4)" ::: "memory");  // kt landed; kt+1 in flight
    } else {
      asm volatile("s_waitcnt vmcnt(0)" ::: "memory");
    }
    asm volatile("s_waitcnt lgkmcnt(0)" ::: "memory");
    __builtin_amdgcn_s_barrier();
    __builtin_amdgcn_sched_barrier(0);

    const u16* Kc = &Kl[kt & 1][0];
    const u16* Vc = &Vl[kt & 1][0];

    // mask words: q-row = qg*16 + fq*4 + r; words kt*4 + kh*2 .. +1
    uint2 mq[4];
#pragma unroll
    for (int r = 0; r < 4; r++)
      mq[r] = *(const uint2*)&Ms[qg * 16 + fq * 4 + r][kt * 4 + kh * 2];

    // ---- QK^T (wave's 64 keys) + mask + exp -> Ps ----
#pragma unroll
    for (int jb = 0; jb < 4; jb++) {
      f32x4 s = (f32x4){0.f, 0.f, 0.f, 0.f};
      const int R = kh * 64 + jb * 16 + fr;   // R&7 == fr&7
      const half8v b0 = *(const half8v*)&Kc[R * 64 + (fq ^ (fr & 7)) * 8];
      const half8v b1 = *(const half8v*)&Kc[R * 64 + ((4 + fq) ^ (fr & 7)) * 8];
      s = __builtin_amdgcn_mfma_f32_16x16x32_f16(qa0, b0, s, 0, 0, 0);
      s = __builtin_amdgcn_mfma_f32_16x16x32_f16(qa1, b1, s, 0, 0, 0);
#pragma unroll
      for (int r = 0; r < 4; r++) {
        const uint mw = (jb >> 1) ? mq[r].y : mq[r].x;
        const float p = ((mw >> ((jb & 1) * 16 + fr)) & 1u)
                            ? __expf(s[r] * 0.03125f) : 0.f;
        lsum[r] += p;
        Ps[wid][fq * 4 + r][jb * 16 + fr] = f2h_bits(p);
      }
    }
    asm volatile("s_waitcnt lgkmcnt(0)" ::: "memory");
    __builtin_amdgcn_sched_barrier(0);

    // ---- PV over the wave's 64 keys (pure MFMA cluster) ----
    __builtin_amdgcn_s_setprio(1);
#pragma unroll
    for (int jc = 0; jc < 2; jc++) {
      const half8v pa = *(const half8v*)&Ps[wid][fr][jc * 32 + fq * 8];
#pragma unroll
      for (int ds = 0; ds < 4; ds++) {
        const int d = ds * 16 + fr;   // d&15 == fr
        const half8v vb =
            *(const half8v*)&Vc[d * 128 + ((kh * 8 + jc * 4 + fq) ^ fr) * 8];
        oacc[ds] = __builtin_amdgcn_mfma_f32_16x16x32_f16(pa, vb, oacc[ds], 0, 0, 0);
      }
    }
    __builtin_amdgcn_s_setprio(0);
    __builtin_amdgcn_s_barrier();   // all waves done reading buf[kt&1]
  }

  // ---- reduce lsum across fr within each 16-lane group ----
#pragma unroll
  for (int r = 0; r < 4; r++) {
    float v = lsum[r];
#pragma unroll
    for (int off = 1; off < 16; off <<= 1) v += __shfl_xor(v, off, 16);
    lsum[r] = v;
  }

  // ---- cross-wave combine: kh=1 publishes, kh=0 finalizes ----
  if (kh == 1) {
#pragma unroll
    for (int ds = 0; ds < 4; ds++)
#pragma unroll
      for (int r = 0; r < 4; r++)
        Obuf[qg][fq * 4 + r][ds * 16 + fr] = oacc[ds][r];
    if (fr == 0) {
#pragma unroll
      for (int r = 0; r < 4; r++) Lbuf[qg][fq * 4 + r] = lsum[r];
    }
  }
  __syncthreads();
  if (kh == 0) {
    float ls[4];
#pragma unroll
    for (int r = 0; r < 4; r++) ls[r] = lsum[r] + Lbuf[qg][fq * 4 + r];
#pragma unroll
    for (int ds = 0; ds < 4; ds++) {
#pragma unroll
      for (int r = 0; r < 4; r++) {
        const float v = oacc[ds][r] + Obuf[qg][fq * 4 + r][ds * 16 + fr];
        O[(size_t)(qt * 64 + qg * 16 + fq * 4 + r) * EMB + h * HD + ds * 16 + fr] =
            f2h_bits(v / ls[r]);
      }
    }
  }
}

extern "C" void kernel_launch(void* const* d_in, const int* in_sizes, int n_in,
                              void* d_out, int out_size, void* d_ws, size_t ws_size,
                              hipStream_t stream) {
  const float* query = (const float*)d_in[0];
  const float* key   = (const float*)d_in[1];
  const float* value = (const float*)d_in[2];
  const float* Wq    = (const float*)d_in[3];
  const float* bq    = (const float*)d_in[4];
  const float* Wk    = (const float*)d_in[5];
  const float* bk    = (const float*)d_in[6];
  const float* Wv    = (const float*)d_in[7];
  const float* bv    = (const float*)d_in[8];
  const float* Wo    = (const float*)d_in[9];
  const float* bo    = (const float*)d_in[10];
  const int* samples = (const int*)d_in[11];
  float* out = (float*)d_out;

  u16* base = (u16*)d_ws;
  u16* Xh = base;
  u16* Wh = base + ((size_t)3 << 20);
  u16* Qh = base + ((size_t)7 << 20);
  u16* Kh = base + ((size_t)8 << 20);
  u16* Vt = base + ((size_t)9 << 20);
  u16* O  = base + ((size_t)10 << 20);
  uint* maskg = (uint*)(base + ((size_t)11 << 20));

  cvt_mask<<<dim3(1024, 8), 256, 0, stream>>>(
      query, key, value, Wq, Wk, Wv, Wo, samples, Xh, maskg);

  gemm3<true><<<dim3(16, 16, 3), 256, 0, stream>>>(Xh, Wh, bq, bk, bv, Qh);

  attn14<<<dim3(NH, 16), 512, 0, stream>>>(Qh, Kh, Vt, maskg, O);

  gemm3<false><<<dim3(16, 16, 1), 256, 0, stream>>>(O, Wh + ((size_t)3 << 20), bo, bo, bo, out);
}

// Round 20
// 56.217 us; speedup vs baseline: 1.2015x; 1.0174x over previous
//
#include <hip/hip_runtime.h>
#include <hip/hip_bf16.h>

#define NTOK 1024
#define EMB  1024
#define NH   16
#define HD   64
#define NS   128

typedef unsigned short u16;
typedef unsigned int uint;
typedef __attribute__((ext_vector_type(8))) unsigned short ushort8v;
typedef __attribute__((ext_vector_type(8))) _Float16 half8v;
typedef __attribute__((ext_vector_type(4))) float f32x4;

__device__ __forceinline__ u16 f2h_bits(float f) {
  union { _Float16 h; u16 u; } x; x.h = (_Float16)f; return x.u;
}

__device__ __forceinline__ void gload16(const u16* g, u16* l) {
  __builtin_amdgcn_global_load_lds(
      (const __attribute__((address_space(1))) uint*)g,
      (__attribute__((address_space(3))) uint*)l, 16, 0, 0);
}

// ---------------------------------------------------------------------------
// cvt_mask: z 0-2 = query/key/value fp32->f16, z 3-6 = Wq/Wk/Wv/Wo fp32->f16,
// z 7 = sampled-set bitmask build (frozen from R11).
// ---------------------------------------------------------------------------
__global__ __launch_bounds__(256) void cvt_mask(const float* __restrict__ S0,
                                                const float* __restrict__ S1,
                                                const float* __restrict__ S2,
                                                const float* __restrict__ S3,
                                                const float* __restrict__ S4,
                                                const float* __restrict__ S5,
                                                const float* __restrict__ S6,
                                                const int* __restrict__ samples,
                                                u16* __restrict__ D,
                                                uint* __restrict__ maskg) {
  const int z = blockIdx.y;
  const int t = threadIdx.x;
  if (z == 7) {
    __shared__ uint m[32];
    const int i = blockIdx.x;
    if (t < 32) m[t] = 0u;
    __syncthreads();
    if (t < NS) {
      const int c = samples[(size_t)i * NS + t];
      atomicOr(&m[c >> 5], 1u << (c & 31));
    }
    __syncthreads();
    if (t < 32) maskg[(size_t)i * 32 + t] = m[t];
    return;
  }
  const float* S;
  switch (z) {
    case 0: S = S0; break;
    case 1: S = S1; break;
    case 2: S = S2; break;
    case 3: S = S3; break;
    case 4: S = S4; break;
    case 5: S = S5; break;
    default: S = S6; break;
  }
  const int idx = blockIdx.x * 256 + t;
  const float4 f = ((const float4*)S)[idx];
  ushort4 p;
  p.x = f2h_bits(f.x); p.y = f2h_bits(f.y);
  p.z = f2h_bits(f.z); p.w = f2h_bits(f.w);
  ((ushort4*)(D + ((size_t)z << 20)))[idx] = p;
}

// ---------------------------------------------------------------------------
// gemm3: counted-vmcnt double-buffered 64x64 f16 GEMM (frozen from R11).
// ---------------------------------------------------------------------------
template<bool OUT_F16>
__global__ __launch_bounds__(256) void gemm3(const u16* __restrict__ Ab,
                                             const u16* __restrict__ Bb,
                                             const float* __restrict__ b0,
                                             const float* __restrict__ b1,
                                             const float* __restrict__ b2,
                                             void* __restrict__ Cp) {
  __shared__ u16 buf[2][2][64 * 32];

  const int t = threadIdx.x;
  const int lane = t & 63;
  const int w = t >> 6;
  const int wr = w >> 1, wc = w & 1;
  const int m0 = blockIdx.y * 64;
  const int n0 = blockIdx.x * 64;
  const int z = blockIdx.z;

  const u16* Az = Ab + ((size_t)z << 20);
  const u16* Bz = Bb + ((size_t)z << 20);
  const float* bsel = (z == 0) ? b0 : ((z == 1) ? b1 : b2);

  const int r_abs = w * 16 + (lane >> 2);
  const int schunk = (lane & 3) ^ ((r_abs >> 1) & 3);
  const u16* gA = Az + (size_t)(m0 + r_abs) * 1024 + schunk * 8;
  const u16* gB = Bz + (size_t)(n0 + r_abs) * 1024 + schunk * 8;
  u16* ldsA[2] = { &buf[0][0][(w * 16) * 32], &buf[1][0][(w * 16) * 32] };
  u16* ldsB[2] = { &buf[0][1][(w * 16) * 32], &buf[1][1][(w * 16) * 32] };

  const int fr = lane & 15;
  const int fq = lane >> 4;
  int offA[2], offB[2];
#pragma unroll
  for (int m = 0; m < 2; m++) {
    const int R = wr * 32 + m * 16 + fr;
    offA[m] = R * 32 + (fq ^ ((R >> 1) & 3)) * 8;
  }
#pragma unroll
  for (int n = 0; n < 2; n++) {
    const int R = wc * 32 + n * 16 + fr;
    offB[n] = R * 32 + (fq ^ ((R >> 1) & 3)) * 8;
  }

  f32x4 acc[2][2];
#pragma unroll
  for (int m = 0; m < 2; m++)
#pragma unroll
    for (int n = 0; n < 2; n++) acc[m][n] = (f32x4){0.f, 0.f, 0.f, 0.f};

  gload16(gA, ldsA[0]);
  gload16(gB, ldsB[0]);

  for (int kt = 0; kt < 32; kt++) {
    const int db = kt & 1;
    if (kt < 31) {
      const int k1 = (kt + 1) * 32;
      gload16(gA + k1, ldsA[db ^ 1]);
      gload16(gB + k1, ldsB[db ^ 1]);
      asm volatile("s_waitcnt vmcnt(2)" ::: "memory");
    } else {
      asm volatile("s_waitcnt vmcnt(0)" ::: "memory");
    }
    __builtin_amdgcn_s_barrier();
    __builtin_amdgcn_sched_barrier(0);

    const u16* cA = &buf[db][0][0];
    const u16* cB = &buf[db][1][0];
    half8v a0 = *(const half8v*)&cA[offA[0]];
    half8v a1 = *(const half8v*)&cA[offA[1]];
    half8v bv0 = *(const half8v*)&cB[offB[0]];
    half8v bv1 = *(const half8v*)&cB[offB[1]];
    acc[0][0] = __builtin_amdgcn_mfma_f32_16x16x32_f16(a0, bv0, acc[0][0], 0, 0, 0);
    acc[0][1] = __builtin_amdgcn_mfma_f32_16x16x32_f16(a0, bv1, acc[0][1], 0, 0, 0);
    acc[1][0] = __builtin_amdgcn_mfma_f32_16x16x32_f16(a1, bv0, acc[1][0], 0, 0, 0);
    acc[1][1] = __builtin_amdgcn_mfma_f32_16x16x32_f16(a1, bv1, acc[1][1], 0, 0, 0);

    asm volatile("s_waitcnt lgkmcnt(0)" ::: "memory");
    __builtin_amdgcn_s_barrier();
    __builtin_amdgcn_sched_barrier(0);
  }

  u16*   Cb = (u16*)Cp   + ((size_t)z << 20);
  float* Cf = (float*)Cp + ((size_t)z << 20);

  if (OUT_F16 && z == 2) {
#pragma unroll
    for (int n = 0; n < 2; n++) {
      const int col = n0 + wc * 32 + n * 16 + fr;
      const float bn = bsel[col];
#pragma unroll
      for (int m = 0; m < 2; m++) {
        const int rbase = m0 + wr * 32 + m * 16 + fq * 4;
        ushort4 pk;
        pk.x = f2h_bits(acc[m][n][0] + bn);
        pk.y = f2h_bits(acc[m][n][1] + bn);
        pk.z = f2h_bits(acc[m][n][2] + bn);
        pk.w = f2h_bits(acc[m][n][3] + bn);
        *(ushort4*)&Cb[(size_t)col * 1024 + rbase] = pk;
      }
    }
    return;
  }

#pragma unroll
  for (int n = 0; n < 2; n++) {
    const int col = n0 + wc * 32 + n * 16 + fr;
    const float bn = bsel[col];
#pragma unroll
    for (int m = 0; m < 2; m++) {
      const int rbase = m0 + wr * 32 + m * 16 + fq * 4;
#pragma unroll
      for (int r = 0; r < 4; r++) {
        const float val = acc[m][n][r] + bn;
        if constexpr (OUT_F16)
          Cb[(size_t)(rbase + r) * 1024 + col] = f2h_bits(val);
        else
          Cf[(size_t)(rbase + r) * 1024 + col] = val;
      }
    }
  }
}

// ---------------------------------------------------------------------------
// attn15: attn14's validated 8-wave structure (2 waves/SIMD, double-buffered
// K/V, counted vmcnt) + attn13's validated swapped-operand scoring:
//   S^T = mfma(K_frag, Q_frag) -> D[key][q]: col=fr=q, rows = 4 CONSECUTIVE
//   keys (fq*4+r). Ps write: one b64 per jb (4 vs 16 scalar u16 stores);
//   mask: ONE uint2 per lane per tile (q=fr lane-invariant); lsum = per-lane
//   scalar (2 shfl_xor + LDS redistribute). PV/staging/epilogue unchanged.
// ---------------------------------------------------------------------------
__global__ __launch_bounds__(512) void attn15(const u16* __restrict__ Qh,
                                              const u16* __restrict__ Kh,
                                              const u16* __restrict__ Vtg,
                                              const uint* __restrict__ maskg,
                                              u16* __restrict__ O) {
  const int h  = blockIdx.x;
  const int qt = blockIdx.y;
  const int t  = threadIdx.x;
  const int wid = t >> 6;          // 0..7
  const int qg  = wid >> 1;        // q-row group 0..3
  const int kh  = wid & 1;         // key half 0..1
  const int lane = t & 63;
  const int fr = lane & 15, fq = lane >> 4;

  __shared__ u16 Kl[2][128 * 64];    // 32 KB  [key][d] swizzled
  __shared__ u16 Vl[2][64 * 128];    // 32 KB  [d][key] swizzled
  __shared__ u16 Ps[8][16][72];      // 18.4 KB per-wave P [q][key-half]
  __shared__ uint Ms[64][36];        // 9.2 KB mask (row stride 144B)
  __shared__ float Obuf[4][16][64];  // 16 KB partial O (kh=1 -> kh=0)
  __shared__ float Lb2[8][16];       // per-wave lsum[q]

  // ---- stage mask: 512 uint4 (one per thread) ----
  {
    const uint4* src = (const uint4*)(maskg + (size_t)qt * 64 * 32);
    *(uint4*)&Ms[t >> 3][(t & 7) * 4] = src[t];
  }

  // ---- Q fragments (B-operand of swapped mfma; same load as attn14) ----
  half8v qa0, qa1;
  {
    const u16* qp = Qh + (size_t)(qt * 64 + qg * 16 + fr) * EMB + h * HD + fq * 8;
    qa0 = *(const half8v*)qp;
    qa1 = *(const half8v*)(qp + 32);
  }

  // ---- staging lane constants (identical to attn14) ----
  const int kR3 = lane >> 3;
  const int kChO = ((lane & 7) ^ (kR3 & 7)) * 8;
  const u16* kBase = Kh + h * HD + kChO;
  const int vSub = lane >> 4;
  const int vCh  = lane & 15;
  const u16* vBase = Vtg + (size_t)h * HD * NTOK;

  auto STAGE = [&](int kt_, int b_) {
#pragma unroll
    for (int ii = 0; ii < 2; ii++) {
      const int row = wid * 16 + ii * 8 + kR3;
      gload16(kBase + (size_t)(kt_ * 128 + row) * EMB,
              &Kl[b_][(wid * 16 + ii * 8) * 64]);
    }
#pragma unroll
    for (int ii = 0; ii < 2; ii++) {
      const int d = wid * 8 + ii * 4 + vSub;
      const int ch = (vCh ^ (d & 15)) * 8;
      gload16(vBase + (size_t)d * NTOK + kt_ * 128 + ch,
              &Vl[b_][(wid * 8 + ii * 4) * 128]);
    }
  };

  f32x4 oacc[4];
#pragma unroll
  for (int ds = 0; ds < 4; ds++) oacc[ds] = (f32x4){0.f, 0.f, 0.f, 0.f};
  float lsum = 0.f;

  STAGE(0, 0);

  for (int kt = 0; kt < 8; kt++) {
    if (kt < 7) {
      STAGE(kt + 1, (kt + 1) & 1);
      asm volatile("s_waitcnt vmcnt(4)" ::: "memory");  // kt landed; kt+1 in flight
    } else {
      asm volatile("s_waitcnt vmcnt(0)" ::: "memory");
    }
    asm volatile("s_waitcnt lgkmcnt(0)" ::: "memory");
    __builtin_amdgcn_s_barrier();
    __builtin_amdgcn_sched_barrier(0);

    const u16* Kc = &Kl[kt & 1][0];
    const u16* Vc = &Vl[kt & 1][0];

    // one mask uint2 per lane per tile: q = qg*16+fr, words kt*4+kh*2..+1
    const uint2 mq = *(const uint2*)&Ms[qg * 16 + fr][kt * 4 + kh * 2];

    // ---- S^T = K·Q^T + mask + exp -> Ps (packed b64 writes) ----
#pragma unroll
    for (int jb = 0; jb < 4; jb++) {
      f32x4 s = (f32x4){0.f, 0.f, 0.f, 0.f};
      const int R = kh * 64 + jb * 16 + fr;   // R&7 == fr&7
      const half8v b0 = *(const half8v*)&Kc[R * 64 + (fq ^ (fr & 7)) * 8];
      const half8v b1 = *(const half8v*)&Kc[R * 64 + ((4 + fq) ^ (fr & 7)) * 8];
      s = __builtin_amdgcn_mfma_f32_16x16x32_f16(b0, qa0, s, 0, 0, 0);
      s = __builtin_amdgcn_mfma_f32_16x16x32_f16(b1, qa1, s, 0, 0, 0);
      const uint mw = (jb >> 1) ? mq.y : mq.x;
      const int bb = (jb & 1) * 16 + fq * 4;
      ushort4 pk;
#pragma unroll
      for (int r = 0; r < 4; r++) {
        const float p = ((mw >> (bb + r)) & 1u) ? __expf(s[r] * 0.03125f) : 0.f;
        lsum += p;
        ((u16*)&pk)[r] = f2h_bits(p);
      }
      *(ushort4*)&Ps[wid][fr][jb * 16 + fq * 4] = pk;
    }
    asm volatile("s_waitcnt lgkmcnt(0)" ::: "memory");
    __builtin_amdgcn_sched_barrier(0);

    // ---- PV over the wave's 64 keys (pure MFMA cluster; unchanged) ----
    __builtin_amdgcn_s_setprio(1);
#pragma unroll
    for (int jc = 0; jc < 2; jc++) {
      const half8v pa = *(const half8v*)&Ps[wid][fr][jc * 32 + fq * 8];
#pragma unroll
      for (int ds = 0; ds < 4; ds++) {
        const int d = ds * 16 + fr;   // d&15 == fr
        const half8v vb =
            *(const half8v*)&Vc[d * 128 + ((kh * 8 + jc * 4 + fq) ^ fr) * 8];
        oacc[ds] = __builtin_amdgcn_mfma_f32_16x16x32_f16(pa, vb, oacc[ds], 0, 0, 0);
      }
    }
    __builtin_amdgcn_s_setprio(0);
    __builtin_amdgcn_s_barrier();   // all waves done reading buf[kt&1]
  }

  // ---- lsum: lane holds partial for q=fr over its (fq) key slice ----
  lsum += __shfl_xor(lsum, 16, 64);
  lsum += __shfl_xor(lsum, 32, 64);
  if (fq == 0) Lb2[wid][fr] = lsum;

  // ---- cross-wave combine: kh=1 publishes O, kh=0 finalizes ----
  if (kh == 1) {
#pragma unroll
    for (int ds = 0; ds < 4; ds++)
#pragma unroll
      for (int r = 0; r < 4; r++)
        Obuf[qg][fq * 4 + r][ds * 16 + fr] = oacc[ds][r];
  }
  __syncthreads();
  if (kh == 0) {
    float ls[4];
#pragma unroll
    for (int r = 0; r < 4; r++)
      ls[r] = Lb2[qg * 2][fq * 4 + r] + Lb2[qg * 2 + 1][fq * 4 + r];
#pragma unroll
    for (int ds = 0; ds < 4; ds++) {
#pragma unroll
      for (int r = 0; r < 4; r++) {
        const float v = oacc[ds][r] + Obuf[qg][fq * 4 + r][ds * 16 + fr];
        O[(size_t)(qt * 64 + qg * 16 + fq * 4 + r) * EMB + h * HD + ds * 16 + fr] =
            f2h_bits(v / ls[r]);
      }
    }
  }
}

extern "C" void kernel_launch(void* const* d_in, const int* in_sizes, int n_in,
                              void* d_out, int out_size, void* d_ws, size_t ws_size,
                              hipStream_t stream) {
  const float* query = (const float*)d_in[0];
  const float* key   = (const float*)d_in[1];
  const float* value = (const float*)d_in[2];
  const float* Wq    = (const float*)d_in[3];
  const float* bq    = (const float*)d_in[4];
  const float* Wk    = (const float*)d_in[5];
  const float* bk    = (const float*)d_in[6];
  const float* Wv    = (const float*)d_in[7];
  const float* bv    = (const float*)d_in[8];
  const float* Wo    = (const float*)d_in[9];
  const float* bo    = (const float*)d_in[10];
  const int* samples = (const int*)d_in[11];
  float* out = (float*)d_out;

  u16* base = (u16*)d_ws;
  u16* Xh = base;
  u16* Wh = base + ((size_t)3 << 20);
  u16* Qh = base + ((size_t)7 << 20);
  u16* Kh = base + ((size_t)8 << 20);
  u16* Vt = base + ((size_t)9 << 20);
  u16* O  = base + ((size_t)10 << 20);
  uint* maskg = (uint*)(base + ((size_t)11 << 20));

  cvt_mask<<<dim3(1024, 8), 256, 0, stream>>>(
      query, key, value, Wq, Wk, Wv, Wo, samples, Xh, maskg);

  gemm3<true><<<dim3(16, 16, 3), 256, 0, stream>>>(Xh, Wh, bq, bk, bv, Qh);

  attn15<<<dim3(NH, 16), 512, 0, stream>>>(Qh, Kh, Vt, maskg, O);

  gemm3<false><<<dim3(16, 16, 1), 256, 0, stream>>>(O, Wh + ((size_t)3 << 20), bo, bo, bo, out);
}

// Round 21
// 52.281 us; speedup vs baseline: 1.2920x; 1.0753x over previous
//
#include <hip/hip_runtime.h>
#include <hip/hip_bf16.h>

#define NTOK 1024
#define EMB  1024
#define NH   16
#define HD   64
#define NS   128

typedef unsigned short u16;
typedef unsigned int uint;
typedef __attribute__((ext_vector_type(8))) unsigned short ushort8v;
typedef __attribute__((ext_vector_type(8))) _Float16 half8v;
typedef __attribute__((ext_vector_type(4))) float f32x4;

__device__ __forceinline__ u16 f2h_bits(float f) {
  union { _Float16 h; u16 u; } x; x.h = (_Float16)f; return x.u;
}

__device__ __forceinline__ void gload16(const u16* g, u16* l) {
  __builtin_amdgcn_global_load_lds(
      (const __attribute__((address_space(1))) uint*)g,
      (__attribute__((address_space(3))) uint*)l, 16, 0, 0);
}

// ---------------------------------------------------------------------------
// cvt_mask: z 0-2 = query/key/value fp32->f16, z 3-6 = Wq/Wk/Wv/Wo fp32->f16,
// z 7 = sampled-set bitmask build (frozen from R11).
// ---------------------------------------------------------------------------
__global__ __launch_bounds__(256) void cvt_mask(const float* __restrict__ S0,
                                                const float* __restrict__ S1,
                                                const float* __restrict__ S2,
                                                const float* __restrict__ S3,
                                                const float* __restrict__ S4,
                                                const float* __restrict__ S5,
                                                const float* __restrict__ S6,
                                                const int* __restrict__ samples,
                                                u16* __restrict__ D,
                                                uint* __restrict__ maskg) {
  const int z = blockIdx.y;
  const int t = threadIdx.x;
  if (z == 7) {
    __shared__ uint m[32];
    const int i = blockIdx.x;
    if (t < 32) m[t] = 0u;
    __syncthreads();
    if (t < NS) {
      const int c = samples[(size_t)i * NS + t];
      atomicOr(&m[c >> 5], 1u << (c & 31));
    }
    __syncthreads();
    if (t < 32) maskg[(size_t)i * 32 + t] = m[t];
    return;
  }
  const float* S;
  switch (z) {
    case 0: S = S0; break;
    case 1: S = S1; break;
    case 2: S = S2; break;
    case 3: S = S3; break;
    case 4: S = S4; break;
    case 5: S = S5; break;
    default: S = S6; break;
  }
  const int idx = blockIdx.x * 256 + t;
  const float4 f = ((const float4*)S)[idx];
  ushort4 p;
  p.x = f2h_bits(f.x); p.y = f2h_bits(f.y);
  p.z = f2h_bits(f.z); p.w = f2h_bits(f.w);
  ((ushort4*)(D + ((size_t)z << 20)))[idx] = p;
}

// ---------------------------------------------------------------------------
// gemm5: counted-vmcnt double-buffered f16 GEMM, BK=64 (vs gemm3's 32).
// 16 K-steps instead of 32: half the barrier drains, 8 MFMA/wave/step.
// Staging: 2 gloads/thread per operand per step (vmcnt(4) keeps next tile
// in flight across the barrier). LDS 32 KB/block -> 3+ blocks/CU.
// Swizzle: LDS[row][c] = G[row][c ^ (row&7)] (chunk 0..7, involution both
// sides; 128B row stride = exact bank wrap, 2-way conflicts = free).
// OUT_F16 && z==2 stores C transposed (Vt[d][token]).
// ---------------------------------------------------------------------------
template<bool OUT_F16>
__global__ __launch_bounds__(256) void gemm5(const u16* __restrict__ Ab,
                                             const u16* __restrict__ Bb,
                                             const float* __restrict__ b0,
                                             const float* __restrict__ b1,
                                             const float* __restrict__ b2,
                                             void* __restrict__ Cp) {
  __shared__ u16 As[2][64 * 64];   // 16 KB per buffer
  __shared__ u16 Bs[2][64 * 64];

  const int t = threadIdx.x;
  const int lane = t & 63;
  const int w = t >> 6;
  const int wr = w >> 1, wc = w & 1;
  const int m0 = blockIdx.y * 64;
  const int n0 = blockIdx.x * 64;
  const int z = blockIdx.z;

  const u16* Az = Ab + ((size_t)z << 20);
  const u16* Bz = Bb + ((size_t)z << 20);
  const float* bsel = (z == 0) ? b0 : ((z == 1) ? b1 : b2);

  // ---- staging: wave w stages rows w*16..w*16+15 (2 gloads per operand) ----
  const int sR  = lane >> 3;                  // 0..7 (row within 8-group)
  const int chO = ((lane & 7) ^ sR) * 8;      // pre-swizzled source chunk
  const int row0 = w * 16 + sR;               // rows w*16..+7   (row&7 == sR)
  const int row1 = row0 + 8;                  // rows w*16+8..+15 (row&7 == sR)
  const u16* gA0 = Az + (size_t)(m0 + row0) * 1024 + chO;
  const u16* gA1 = Az + (size_t)(m0 + row1) * 1024 + chO;
  const u16* gB0 = Bz + (size_t)(n0 + row0) * 1024 + chO;
  const u16* gB1 = Bz + (size_t)(n0 + row1) * 1024 + chO;

  // ---- fragment read offsets: LDS c = kchunk ^ (R&7), kchunk = kk*4+fq ----
  const int fr = lane & 15;
  const int fq = lane >> 4;
  int offA[2][2], offB[2][2];
#pragma unroll
  for (int m = 0; m < 2; m++) {
    const int R = wr * 32 + m * 16 + fr;
#pragma unroll
    for (int kk = 0; kk < 2; kk++)
      offA[m][kk] = R * 64 + (((kk * 4 + fq) ^ (R & 7)) * 8);
  }
#pragma unroll
  for (int n = 0; n < 2; n++) {
    const int R = wc * 32 + n * 16 + fr;
#pragma unroll
    for (int kk = 0; kk < 2; kk++)
      offB[n][kk] = R * 64 + (((kk * 4 + fq) ^ (R & 7)) * 8);
  }

  f32x4 acc[2][2];
#pragma unroll
  for (int m = 0; m < 2; m++)
#pragma unroll
    for (int n = 0; n < 2; n++) acc[m][n] = (f32x4){0.f, 0.f, 0.f, 0.f};

  // prologue: stage tile 0
  gload16(gA0, &As[0][(size_t)row0 * 64 - (size_t)sR * 64]);  // base w*16 rows
  gload16(gA1, &As[0][(size_t)(w * 16 + 8) * 64]);
  gload16(gB0, &Bs[0][(size_t)(w * 16) * 64]);
  gload16(gB1, &Bs[0][(size_t)(w * 16 + 8) * 64]);

  for (int kt = 0; kt < 16; kt++) {
    const int db = kt & 1;
    if (kt < 15) {
      const int k1 = (kt + 1) * 64;
      gload16(gA0 + k1, &As[db ^ 1][(size_t)(w * 16) * 64]);
      gload16(gA1 + k1, &As[db ^ 1][(size_t)(w * 16 + 8) * 64]);
      gload16(gB0 + k1, &Bs[db ^ 1][(size_t)(w * 16) * 64]);
      gload16(gB1 + k1, &Bs[db ^ 1][(size_t)(w * 16 + 8) * 64]);
      asm volatile("s_waitcnt vmcnt(4)" ::: "memory");  // kt landed; kt+1 in flight
    } else {
      asm volatile("s_waitcnt vmcnt(0)" ::: "memory");
    }
    __builtin_amdgcn_s_barrier();
    __builtin_amdgcn_sched_barrier(0);

#pragma unroll
    for (int kk = 0; kk < 2; kk++) {
      half8v a0 = *(const half8v*)&As[db][offA[0][kk]];
      half8v a1 = *(const half8v*)&As[db][offA[1][kk]];
      half8v bv0 = *(const half8v*)&Bs[db][offB[0][kk]];
      half8v bv1 = *(const half8v*)&Bs[db][offB[1][kk]];
      acc[0][0] = __builtin_amdgcn_mfma_f32_16x16x32_f16(a0, bv0, acc[0][0], 0, 0, 0);
      acc[0][1] = __builtin_amdgcn_mfma_f32_16x16x32_f16(a0, bv1, acc[0][1], 0, 0, 0);
      acc[1][0] = __builtin_amdgcn_mfma_f32_16x16x32_f16(a1, bv0, acc[1][0], 0, 0, 0);
      acc[1][1] = __builtin_amdgcn_mfma_f32_16x16x32_f16(a1, bv1, acc[1][1], 0, 0, 0);
    }

    asm volatile("s_waitcnt lgkmcnt(0)" ::: "memory");
    __builtin_amdgcn_s_barrier();
    __builtin_amdgcn_sched_barrier(0);
  }

  u16*   Cb = (u16*)Cp   + ((size_t)z << 20);
  float* Cf = (float*)Cp + ((size_t)z << 20);

  if (OUT_F16 && z == 2) {
#pragma unroll
    for (int n = 0; n < 2; n++) {
      const int col = n0 + wc * 32 + n * 16 + fr;
      const float bn = bsel[col];
#pragma unroll
      for (int m = 0; m < 2; m++) {
        const int rbase = m0 + wr * 32 + m * 16 + fq * 4;
        ushort4 pk;
        pk.x = f2h_bits(acc[m][n][0] + bn);
        pk.y = f2h_bits(acc[m][n][1] + bn);
        pk.z = f2h_bits(acc[m][n][2] + bn);
        pk.w = f2h_bits(acc[m][n][3] + bn);
        *(ushort4*)&Cb[(size_t)col * 1024 + rbase] = pk;
      }
    }
    return;
  }

#pragma unroll
  for (int n = 0; n < 2; n++) {
    const int col = n0 + wc * 32 + n * 16 + fr;
    const float bn = bsel[col];
#pragma unroll
    for (int m = 0; m < 2; m++) {
      const int rbase = m0 + wr * 32 + m * 16 + fq * 4;
#pragma unroll
      for (int r = 0; r < 4; r++) {
        const float val = acc[m][n][r] + bn;
        if constexpr (OUT_F16)
          Cb[(size_t)(rbase + r) * 1024 + col] = f2h_bits(val);
        else
          Cf[(size_t)(rbase + r) * 1024 + col] = val;
      }
    }
  }
}

// ---------------------------------------------------------------------------
// attn15 (frozen from R20): 8-wave blocks (2 waves/SIMD), double-buffered
// K/V with counted vmcnt, swapped-operand scoring, packed Ps writes.
// ---------------------------------------------------------------------------
__global__ __launch_bounds__(512) void attn15(const u16* __restrict__ Qh,
                                              const u16* __restrict__ Kh,
                                              const u16* __restrict__ Vtg,
                                              const uint* __restrict__ maskg,
                                              u16* __restrict__ O) {
  const int h  = blockIdx.x;
  const int qt = blockIdx.y;
  const int t  = threadIdx.x;
  const int wid = t >> 6;          // 0..7
  const int qg  = wid >> 1;        // q-row group 0..3
  const int kh  = wid & 1;         // key half 0..1
  const int lane = t & 63;
  const int fr = lane & 15, fq = lane >> 4;

  __shared__ u16 Kl[2][128 * 64];
  __shared__ u16 Vl[2][64 * 128];
  __shared__ u16 Ps[8][16][72];
  __shared__ uint Ms[64][36];
  __shared__ float Obuf[4][16][64];
  __shared__ float Lb2[8][16];

  {
    const uint4* src = (const uint4*)(maskg + (size_t)qt * 64 * 32);
    *(uint4*)&Ms[t >> 3][(t & 7) * 4] = src[t];
  }

  half8v qa0, qa1;
  {
    const u16* qp = Qh + (size_t)(qt * 64 + qg * 16 + fr) * EMB + h * HD + fq * 8;
    qa0 = *(const half8v*)qp;
    qa1 = *(const half8v*)(qp + 32);
  }

  const int kR3 = lane >> 3;
  const int kChO = ((lane & 7) ^ (kR3 & 7)) * 8;
  const u16* kBase = Kh + h * HD + kChO;
  const int vSub = lane >> 4;
  const int vCh  = lane & 15;
  const u16* vBase = Vtg + (size_t)h * HD * NTOK;

  auto STAGE = [&](int kt_, int b_) {
#pragma unroll
    for (int ii = 0; ii < 2; ii++) {
      const int row = wid * 16 + ii * 8 + kR3;
      gload16(kBase + (size_t)(kt_ * 128 + row) * EMB,
              &Kl[b_][(wid * 16 + ii * 8) * 64]);
    }
#pragma unroll
    for (int ii = 0; ii < 2; ii++) {
      const int d = wid * 8 + ii * 4 + vSub;
      const int ch = (vCh ^ (d & 15)) * 8;
      gload16(vBase + (size_t)d * NTOK + kt_ * 128 + ch,
              &Vl[b_][(wid * 8 + ii * 4) * 128]);
    }
  };

  f32x4 oacc[4];
#pragma unroll
  for (int ds = 0; ds < 4; ds++) oacc[ds] = (f32x4){0.f, 0.f, 0.f, 0.f};
  float lsum = 0.f;

  STAGE(0, 0);

  for (int kt = 0; kt < 8; kt++) {
    if (kt < 7) {
      STAGE(kt + 1, (kt + 1) & 1);
      asm volatile("s_waitcnt vmcnt(4)" ::: "memory");
    } else {
      asm volatile("s_waitcnt vmcnt(0)" ::: "memory");
    }
    asm volatile("s_waitcnt lgkmcnt(0)" ::: "memory");
    __builtin_amdgcn_s_barrier();
    __builtin_amdgcn_sched_barrier(0);

    const u16* Kc = &Kl[kt & 1][0];
    const u16* Vc = &Vl[kt & 1][0];

    const uint2 mq = *(const uint2*)&Ms[qg * 16 + fr][kt * 4 + kh * 2];

#pragma unroll
    for (int jb = 0; jb < 4; jb++) {
      f32x4 s = (f32x4){0.f, 0.f, 0.f, 0.f};
      const int R = kh * 64 + jb * 16 + fr;
      const half8v b0 = *(const half8v*)&Kc[R * 64 + (fq ^ (fr & 7)) * 8];
      const half8v b1 = *(const half8v*)&Kc[R * 64 + ((4 + fq) ^ (fr & 7)) * 8];
      s = __builtin_amdgcn_mfma_f32_16x16x32_f16(b0, qa0, s, 0, 0, 0);
      s = __builtin_amdgcn_mfma_f32_16x16x32_f16(b1, qa1, s, 0, 0, 0);
      const uint mw = (jb >> 1) ? mq.y : mq.x;
      const int bb = (jb & 1) * 16 + fq * 4;
      ushort4 pk;
#pragma unroll
      for (int r = 0; r < 4; r++) {
        const float p = ((mw >> (bb + r)) & 1u) ? __expf(s[r] * 0.03125f) : 0.f;
        lsum += p;
        ((u16*)&pk)[r] = f2h_bits(p);
      }
      *(ushort4*)&Ps[wid][fr][jb * 16 + fq * 4] = pk;
    }
    asm volatile("s_waitcnt lgkmcnt(0)" ::: "memory");
    __builtin_amdgcn_sched_barrier(0);

    __builtin_amdgcn_s_setprio(1);
#pragma unroll
    for (int jc = 0; jc < 2; jc++) {
      const half8v pa = *(const half8v*)&Ps[wid][fr][jc * 32 + fq * 8];
#pragma unroll
      for (int ds = 0; ds < 4; ds++) {
        const int d = ds * 16 + fr;
        const half8v vb =
            *(const half8v*)&Vc[d * 128 + ((kh * 8 + jc * 4 + fq) ^ fr) * 8];
        oacc[ds] = __builtin_amdgcn_mfma_f32_16x16x32_f16(pa, vb, oacc[ds], 0, 0, 0);
      }
    }
    __builtin_amdgcn_s_setprio(0);
    __builtin_amdgcn_s_barrier();
  }

  lsum += __shfl_xor(lsum, 16, 64);
  lsum += __shfl_xor(lsum, 32, 64);
  if (fq == 0) Lb2[wid][fr] = lsum;

  if (kh == 1) {
#pragma unroll
    for (int ds = 0; ds < 4; ds++)
#pragma unroll
      for (int r = 0; r < 4; r++)
        Obuf[qg][fq * 4 + r][ds * 16 + fr] = oacc[ds][r];
  }
  __syncthreads();
  if (kh == 0) {
    float ls[4];
#pragma unroll
    for (int r = 0; r < 4; r++)
      ls[r] = Lb2[qg * 2][fq * 4 + r] + Lb2[qg * 2 + 1][fq * 4 + r];
#pragma unroll
    for (int ds = 0; ds < 4; ds++) {
#pragma unroll
      for (int r = 0; r < 4; r++) {
        const float v = oacc[ds][r] + Obuf[qg][fq * 4 + r][ds * 16 + fr];
        O[(size_t)(qt * 64 + qg * 16 + fq * 4 + r) * EMB + h * HD + ds * 16 + fr] =
            f2h_bits(v / ls[r]);
      }
    }
  }
}

extern "C" void kernel_launch(void* const* d_in, const int* in_sizes, int n_in,
                              void* d_out, int out_size, void* d_ws, size_t ws_size,
                              hipStream_t stream) {
  const float* query = (const float*)d_in[0];
  const float* key   = (const float*)d_in[1];
  const float* value = (const float*)d_in[2];
  const float* Wq    = (const float*)d_in[3];
  const float* bq    = (const float*)d_in[4];
  const float* Wk    = (const float*)d_in[5];
  const float* bk    = (const float*)d_in[6];
  const float* Wv    = (const float*)d_in[7];
  const float* bv    = (const float*)d_in[8];
  const float* Wo    = (const float*)d_in[9];
  const float* bo    = (const float*)d_in[10];
  const int* samples = (const int*)d_in[11];
  float* out = (float*)d_out;

  u16* base = (u16*)d_ws;
  u16* Xh = base;
  u16* Wh = base + ((size_t)3 << 20);
  u16* Qh = base + ((size_t)7 << 20);
  u16* Kh = base + ((size_t)8 << 20);
  u16* Vt = base + ((size_t)9 << 20);
  u16* O  = base + ((size_t)10 << 20);
  uint* maskg = (uint*)(base + ((size_t)11 << 20));

  cvt_mask<<<dim3(1024, 8), 256, 0, stream>>>(
      query, key, value, Wq, Wk, Wv, Wo, samples, Xh, maskg);

  gemm5<true><<<dim3(16, 16, 3), 256, 0, stream>>>(Xh, Wh, bq, bk, bv, Qh);

  attn15<<<dim3(NH, 16), 512, 0, stream>>>(Qh, Kh, Vt, maskg, O);

  gemm5<false><<<dim3(16, 16, 1), 256, 0, stream>>>(O, Wh + ((size_t)3 << 20), bo, bo, bo, out);
}